// Round 1
// baseline (80.752 us; speedup 1.0000x reference)
//
#include <hip/hip_runtime.h>
#include <math.h>

// Problem constants
#define NB     16384
#define NJOINT 14
#define NCOL   14
#define NPIX   196            // 14*14
#define NTASKS (NB * NJOINT)  // 229376
#define RAD    4

#define GRID1  2048
#define BLOCK1 256
#define WPB    4                    // waves per block
#define NWAVES (GRID1 * WPB)        // 8192 -> 28 tasks/wave exactly

__global__ __launch_bounds__(BLOCK1) void mse2_main(
    const float* __restrict__ osp,   // [B, 2*NJ, 196]
    const float* __restrict__ h,     // [B, NJ, 196]
    const float* __restrict__ t,     // [B, NJ, 2]
    const float* __restrict__ v,     // [B, NJ, 2]
    double* __restrict__ partials)   // [GRID1*2]
{
    __shared__ float tbl[NCOL * NCOL];   // tbl[p][o]: 1-D gaussian response, delta at p, output o
    __shared__ float rmin[NCOL], rmax[NCOL];
    __shared__ double red[WPB * 2];

    const int tid = threadIdx.x;

    // ---- build the 14x14 separable-gaussian table once per block ----
    if (tid < NPIX) {
        // gaussian kernel, computed like the reference (float64 -> cast f32)
        double kd[2 * RAD + 1];
        double ks = 0.0;
        #pragma unroll
        for (int d = 0; d <= 2 * RAD; ++d) {
            double xx = (double)(d - RAD);
            kd[d] = exp(-0.5 * xx * xx);
            ks += kd[d];
        }
        const int p = tid / NCOL, o = tid % NCOL;
        float s = 0.f;
        #pragma unroll
        for (int d = 0; d <= 2 * RAD; ++d) {
            int i = o + d;                                     // padded index 0..21
            int m = (i < RAD) ? (RAD - 1 - i)                  // symmetric reflect left
                  : (i < RAD + NCOL) ? (i - RAD)
                  : (2 * (RAD + NCOL) - 1 - i - RAD);          // 31 - i
            if (m == p) s += (float)(kd[d] / ks);
        }
        tbl[p * NCOL + o] = s;
    }
    __syncthreads();
    if (tid < NCOL) {
        float mn = tbl[tid * NCOL], mx = mn;
        for (int o = 1; o < NCOL; ++o) {
            float val = tbl[tid * NCOL + o];
            mn = fminf(mn, val);
            mx = fmaxf(mx, val);
        }
        rmin[tid] = mn;
        rmax[tid] = mx;
    }
    __syncthreads();

    const int lane  = tid & 63;
    const int wid   = tid >> 6;
    const int gwave = blockIdx.x * WPB + wid;

    float d1acc = 0.f;   // per-lane, reduced once at the end
    float d2acc = 0.f;   // meaningful on lane 0 only
    float nacc  = 0.f;   // meaningful on lane 0 only

    for (int task = gwave; task < NTASKS; task += NWAVES) {
        const float t0 = t[task * 2 + 0];
        const float t1 = t[task * 2 + 1];
        const float v0 = v[task * 2 + 0];
        const bool vis = ((int)v0) == 1;

        // splat center (trunc + clip, matches reference)
        const int xi = min(NCOL - 1, max(0, (int)(t0 * (float)NCOL)));
        const int yi = min(NCOL - 1, max(0, (int)(t1 * (float)NCOL)));
        const float mn = rmin[yi] * rmin[xi];
        const float mx = rmax[yi] * rmax[xi];
        const float inv = 1.f / (mx - mn);

        const float* __restrict__ hb = h + (size_t)task * NPIX;

        float mval = -1.f;
        int   midx = 0;
        float local = 0.f;

        #pragma unroll
        for (int i = 0; i < 4; ++i) {
            const int el = lane + i * 64;
            if (el < NPIX) {
                const float hv = hb[el];
                const int y = el / NCOL;
                const int x = el - y * NCOL;
                if (hv > mval) { mval = hv; midx = el; }   // ascending el => first-max per lane
                if (vis) {
                    const float gn = (tbl[yi * NCOL + y] * tbl[xi * NCOL + x] - mn) * inv;
                    const float d = hv - gn;
                    local += d * d;
                } else if (y > 0) {                        // row-0 of diff zeroed when invisible
                    local += hv * hv;
                }
            }
        }
        d1acc += local;

        // wave argmax with lower-index tie-break (jnp.argmax first-occurrence)
        #pragma unroll
        for (int off = 32; off; off >>= 1) {
            const float ov = __shfl_xor(mval, off);
            const int   oi = __shfl_xor(midx, off);
            if (ov > mval || (ov == mval && oi < midx)) { mval = ov; midx = oi; }
        }

        if (lane == 0 && vis) {
            nacc += v0;  // N = sum(v)/2 == sum of vis flags
            const int yC = midx / NCOL;
            const int xC = midx - yC * NCOL;
            const long ob = ((long)(task / NJOINT) * (2 * NJOINT) + (task % NJOINT)) * NPIX;
            const float osx = osp[ob + midx];
            const float osy = osp[ob + (long)NJOINT * NPIX + midx];
            const bool cond = mval > 0.5f;
            const float sc = 1.0f / (float)NCOL;
            const float x0 = cond ? (osx + (float)xC) * sc : 0.f;
            const float x1 = cond ? (osy + (float)yC) * sc : 0.f;
            const float dx = x0 - t0;
            const float dy = x1 - t1;
            d2acc += dx * dx + dy * dy;
        }
    }

    // reduce d1 across the wave (deterministic shuffle tree)
    #pragma unroll
    for (int off = 32; off; off >>= 1) d1acc += __shfl_xor(d1acc, off);

    if (lane == 0) {
        red[wid * 2 + 0] = (double)d1acc + (double)d2acc;
        red[wid * 2 + 1] = (double)nacc;
    }
    __syncthreads();
    if (tid == 0) {
        double s = 0.0, n = 0.0;
        #pragma unroll
        for (int w = 0; w < WPB; ++w) { s += red[w * 2]; n += red[w * 2 + 1]; }
        partials[blockIdx.x * 2 + 0] = s;
        partials[blockIdx.x * 2 + 1] = n;
    }
}

__global__ __launch_bounds__(256) void mse2_reduce(const double* __restrict__ partials,
                                                   float* __restrict__ out)
{
    __shared__ double ssum[256], snum[256];
    double s = 0.0, n = 0.0;
    for (int i = threadIdx.x; i < GRID1; i += 256) {
        s += partials[i * 2 + 0];
        n += partials[i * 2 + 1];
    }
    ssum[threadIdx.x] = s;
    snum[threadIdx.x] = n;
    __syncthreads();
    for (int off = 128; off; off >>= 1) {
        if (threadIdx.x < off) {
            ssum[threadIdx.x] += ssum[threadIdx.x + off];
            snum[threadIdx.x] += snum[threadIdx.x + off];
        }
        __syncthreads();
    }
    if (threadIdx.x == 0) out[0] = (float)(ssum[0] / snum[0]);
}

extern "C" void kernel_launch(void* const* d_in, const int* in_sizes, int n_in,
                              void* d_out, int out_size, void* d_ws, size_t ws_size,
                              hipStream_t stream) {
    const float* osp = (const float*)d_in[0];
    const float* h   = (const float*)d_in[1];
    // d_in[2] = op, unused by the reference
    const float* t   = (const float*)d_in[3];
    const float* v   = (const float*)d_in[4];
    double* partials = (double*)d_ws;
    float* out = (float*)d_out;

    mse2_main<<<GRID1, BLOCK1, 0, stream>>>(osp, h, t, v, partials);
    mse2_reduce<<<1, 256, 0, stream>>>(partials, out);
}

// Round 2
// 43.021 us; speedup vs baseline: 1.8770x; 1.8770x over previous
//
#include <hip/hip_runtime.h>
#include <math.h>

// Problem constants
#define NB     16384
#define NJOINT 14
#define NCOL   14
#define NPIX   196            // 14*14 == 49 float4 exactly
#define NTASKS (NB * NJOINT)  // 229376
#define RAD    4

#define BLOCK1 256
#define GRID1  (NTASKS / BLOCK1)   // 896 blocks exactly

__global__ __launch_bounds__(BLOCK1) void mse2_main(
    const float* __restrict__ osp,   // [B, 2*NJ, 196]
    const float* __restrict__ h,     // [B, NJ, 196]
    const float* __restrict__ t,     // [B, NJ, 2]
    const float* __restrict__ v,     // [B, NJ, 2]
    double* __restrict__ partials)   // [GRID1*2]
{
    __shared__ float tbl[NCOL * NCOL];   // tbl[p][o]: 1-D gaussian response, delta at p, output o
    __shared__ float rmin[NCOL], rmax[NCOL];
    __shared__ double sd[BLOCK1], sn[BLOCK1];

    const int tid = threadIdx.x;

    // ---- build the 14x14 separable-gaussian table once per block ----
    if (tid < NPIX) {
        double kd[2 * RAD + 1];
        double ks = 0.0;
        #pragma unroll
        for (int d = 0; d <= 2 * RAD; ++d) {
            double xx = (double)(d - RAD);
            kd[d] = exp(-0.5 * xx * xx);
            ks += kd[d];
        }
        const int p = tid / NCOL, o = tid % NCOL;
        float s = 0.f;
        #pragma unroll
        for (int d = 0; d <= 2 * RAD; ++d) {
            int i = o + d;                                     // padded index 0..21
            int m = (i < RAD) ? (RAD - 1 - i)                  // symmetric reflect left
                  : (i < RAD + NCOL) ? (i - RAD)
                  : (2 * (RAD + NCOL) - 1 - i - RAD);          // 31 - i
            if (m == p) s += (float)(kd[d] / ks);
        }
        tbl[p * NCOL + o] = s;
    }
    __syncthreads();
    if (tid < NCOL) {
        float mnv = tbl[tid * NCOL], mxv = mnv;
        for (int o = 1; o < NCOL; ++o) {
            float val = tbl[tid * NCOL + o];
            mnv = fminf(mnv, val);
            mxv = fmaxf(mxv, val);
        }
        rmin[tid] = mnv;
        rmax[tid] = mxv;
    }
    __syncthreads();

    // ---- one task per thread ----
    const int task = blockIdx.x * BLOCK1 + tid;   // always < NTASKS (exact fit)

    const float t0 = t[task * 2 + 0];
    const float t1 = t[task * 2 + 1];
    const float v0 = v[task * 2 + 0];
    const bool vis = ((int)v0) == 1;

    // splat center (trunc + clip, matches reference)
    const int xi = min(NCOL - 1, max(0, (int)(t0 * (float)NCOL)));
    const int yi = min(NCOL - 1, max(0, (int)(t1 * (float)NCOL)));
    const float mn  = rmin[yi] * rmin[xi];
    const float mx  = rmax[yi] * rmax[xi];
    const float inv = 1.f / (mx - mn);

    // preload gaussian rows into registers (static-indexed after unroll)
    float gyr[NCOL], gxr[NCOL];
    #pragma unroll
    for (int k = 0; k < NCOL; ++k) {
        gyr[k] = tbl[yi * NCOL + k];
        gxr[k] = tbl[xi * NCOL + k];
    }

    const float4* __restrict__ hb4 =
        reinterpret_cast<const float4*>(h + (size_t)task * NPIX);

    float acc  = 0.f;    // d1 partial
    float mval = -1.f;
    int   midx = 0;

    const float visf = vis ? 1.f : 0.f;

    #pragma unroll
    for (int q = 0; q < NPIX / 4; ++q) {
        const float4 hv4 = hb4[q];
        const float ev[4] = {hv4.x, hv4.y, hv4.z, hv4.w};
        #pragma unroll
        for (int j = 0; j < 4; ++j) {
            const int el = 4 * q + j;            // compile-time constant
            const int y = el / NCOL;             // compile-time
            const int x = el - y * NCOL;         // compile-time
            const float hv = ev[j];
            // first-occurrence argmax (ascending el)
            if (hv > mval) { mval = hv; midx = el; }
            // d1: visible -> (h - gn)^2 over all pixels;
            //     invisible -> h^2 except row 0 (diff row-0 zeroed)
            const float gn  = (gyr[y] * gxr[x] - mn) * inv;
            const float tgt = visf * gn;
            const float d   = hv - tgt;
            const float c   = (!vis && y == 0) ? 0.f : d * d;  // y==0 is compile-time
            acc += c;
        }
    }

    // d2 + N contribution (per-thread, no cross-lane needed)
    float d2v = 0.f, nv = 0.f;
    if (vis) {
        nv = v0;   // == 1
        const int yC = midx / NCOL;
        const int xC = midx - yC * NCOL;
        const int b  = task / NJOINT;
        const int j  = task - b * NJOINT;
        const float* __restrict__ ob = osp + ((size_t)b * (2 * NJOINT) + j) * NPIX;
        const float osx = ob[midx];
        const float osy = ob[(size_t)NJOINT * NPIX + midx];
        const bool cond = mval > 0.5f;
        const float sc = 1.0f / (float)NCOL;
        const float x0 = cond ? (osx + (float)xC) * sc : 0.f;
        const float x1 = cond ? (osy + (float)yC) * sc : 0.f;
        const float dx = x0 - t0;
        const float dy = x1 - t1;
        d2v = dx * dx + dy * dy;
    }

    // ---- deterministic block reduction (doubles) ----
    sd[tid] = (double)acc + (double)d2v;
    sn[tid] = (double)nv;
    __syncthreads();
    #pragma unroll
    for (int off = BLOCK1 / 2; off > 0; off >>= 1) {
        if (tid < off) {
            sd[tid] += sd[tid + off];
            sn[tid] += sn[tid + off];
        }
        __syncthreads();
    }
    if (tid == 0) {
        partials[blockIdx.x * 2 + 0] = sd[0];
        partials[blockIdx.x * 2 + 1] = sn[0];
    }
}

__global__ __launch_bounds__(256) void mse2_reduce(const double* __restrict__ partials,
                                                   float* __restrict__ out)
{
    __shared__ double ssum[256], snum[256];
    double s = 0.0, n = 0.0;
    for (int i = threadIdx.x; i < GRID1; i += 256) {
        s += partials[i * 2 + 0];
        n += partials[i * 2 + 1];
    }
    ssum[threadIdx.x] = s;
    snum[threadIdx.x] = n;
    __syncthreads();
    for (int off = 128; off; off >>= 1) {
        if (threadIdx.x < off) {
            ssum[threadIdx.x] += ssum[threadIdx.x + off];
            snum[threadIdx.x] += snum[threadIdx.x + off];
        }
        __syncthreads();
    }
    if (threadIdx.x == 0) out[0] = (float)(ssum[0] / snum[0]);
}

extern "C" void kernel_launch(void* const* d_in, const int* in_sizes, int n_in,
                              void* d_out, int out_size, void* d_ws, size_t ws_size,
                              hipStream_t stream) {
    const float* osp = (const float*)d_in[0];
    const float* h   = (const float*)d_in[1];
    // d_in[2] = op, unused by the reference
    const float* t   = (const float*)d_in[3];
    const float* v   = (const float*)d_in[4];
    double* partials = (double*)d_ws;
    float* out = (float*)d_out;

    mse2_main<<<GRID1, BLOCK1, 0, stream>>>(osp, h, t, v, partials);
    mse2_reduce<<<1, 256, 0, stream>>>(partials, out);
}

// Round 3
// 42.814 us; speedup vs baseline: 1.8861x; 1.0049x over previous
//
#include <hip/hip_runtime.h>
#include <math.h>

// Problem constants
#define NB     16384
#define NJOINT 14
#define NCOL   14
#define NPIX   196            // 14*14 == 49 float4 exactly
#define NTASKS (NB * NJOINT)  // 229376
#define RAD    4

#define BLOCK1 128
#define GRID1  (NTASKS / BLOCK1)   // 1792 blocks = exactly 7 per CU on 256 CUs

__global__ __launch_bounds__(BLOCK1) void mse2_main(
    const float* __restrict__ osp,   // [B, 2*NJ, 196]
    const float* __restrict__ h,     // [B, NJ, 196]
    const float* __restrict__ t,     // [B, NJ, 2]
    const float* __restrict__ v,     // [B, NJ, 2]
    double* __restrict__ partials)   // [GRID1*2]
{
    __shared__ float tbl[NCOL * NCOL];   // tbl[p][o]: 1-D gaussian response, delta at p, output o
    __shared__ float rmin[NCOL], rmax[NCOL];
    __shared__ double sd[BLOCK1], sn[BLOCK1];

    const int tid = threadIdx.x;

    // ---- build the 14x14 separable-gaussian table once per block ----
    for (int e = tid; e < NPIX; e += BLOCK1) {
        double kd[2 * RAD + 1];
        double ks = 0.0;
        #pragma unroll
        for (int d = 0; d <= 2 * RAD; ++d) {
            double xx = (double)(d - RAD);
            kd[d] = exp(-0.5 * xx * xx);
            ks += kd[d];
        }
        const int p = e / NCOL, o = e % NCOL;
        float s = 0.f;
        #pragma unroll
        for (int d = 0; d <= 2 * RAD; ++d) {
            int i = o + d;                                     // padded index 0..21
            int m = (i < RAD) ? (RAD - 1 - i)                  // symmetric reflect left
                  : (i < RAD + NCOL) ? (i - RAD)
                  : (2 * (RAD + NCOL) - 1 - i - RAD);          // 31 - i
            if (m == p) s += (float)(kd[d] / ks);
        }
        tbl[p * NCOL + o] = s;
    }
    __syncthreads();
    if (tid < NCOL) {
        float mnv = tbl[tid * NCOL], mxv = mnv;
        for (int o = 1; o < NCOL; ++o) {
            float val = tbl[tid * NCOL + o];
            mnv = fminf(mnv, val);
            mxv = fmaxf(mxv, val);
        }
        rmin[tid] = mnv;
        rmax[tid] = mxv;
    }
    __syncthreads();

    // ---- one task per thread ----
    const int task = blockIdx.x * BLOCK1 + tid;   // always < NTASKS (exact fit)

    const float2 tv = reinterpret_cast<const float2*>(t)[task];
    const float t0 = tv.x;
    const float t1 = tv.y;
    const float v0 = reinterpret_cast<const float2*>(v)[task].x;
    const bool vis = ((int)v0) == 1;

    // splat center (trunc + clip, matches reference)
    const int xi = min(NCOL - 1, max(0, (int)(t0 * (float)NCOL)));
    const int yi = min(NCOL - 1, max(0, (int)(t1 * (float)NCOL)));
    const float mn  = rmin[yi] * rmin[xi];
    const float mx  = rmax[yi] * rmax[xi];
    const float inv = 1.f / (mx - mn);

    // preload gaussian rows into registers (static-indexed after unroll)
    float gyr[NCOL], gxr[NCOL];
    #pragma unroll
    for (int k = 0; k < NCOL; ++k) {
        gyr[k] = tbl[yi * NCOL + k];
        gxr[k] = tbl[xi * NCOL + k];
    }

    const float4* __restrict__ hb4 =
        reinterpret_cast<const float4*>(h + (size_t)task * NPIX);

    float acc  = 0.f;    // d1 partial
    float mval = -1.f;
    int   midx = 0;

    const float visf = vis ? 1.f : 0.f;

    #pragma unroll
    for (int q = 0; q < NPIX / 4; ++q) {
        const float4 hv4 = hb4[q];
        const float ev[4] = {hv4.x, hv4.y, hv4.z, hv4.w};
        #pragma unroll
        for (int j = 0; j < 4; ++j) {
            const int el = 4 * q + j;            // compile-time constant
            const int y = el / NCOL;             // compile-time
            const int x = el - y * NCOL;         // compile-time
            const float hv = ev[j];
            // first-occurrence argmax (ascending el)
            if (hv > mval) { mval = hv; midx = el; }
            // d1: visible -> (h - gn)^2 over all pixels;
            //     invisible -> h^2 except row 0 (diff row-0 zeroed)
            const float gn  = (gyr[y] * gxr[x] - mn) * inv;
            const float tgt = visf * gn;
            const float d   = hv - tgt;
            const float c   = (!vis && y == 0) ? 0.f : d * d;  // y==0 is compile-time
            acc += c;
        }
    }

    // d2 + N contribution (per-thread, no cross-lane needed)
    float d2v = 0.f, nv = 0.f;
    if (vis) {
        nv = v0;   // == 1
        const int yC = midx / NCOL;
        const int xC = midx - yC * NCOL;
        const int b  = task / NJOINT;
        const int j  = task - b * NJOINT;
        const float* __restrict__ ob = osp + ((size_t)b * (2 * NJOINT) + j) * NPIX;
        const float osx = ob[midx];
        const float osy = ob[(size_t)NJOINT * NPIX + midx];
        const bool cond = mval > 0.5f;
        const float sc = 1.0f / (float)NCOL;
        const float x0 = cond ? (osx + (float)xC) * sc : 0.f;
        const float x1 = cond ? (osy + (float)yC) * sc : 0.f;
        const float dx = x0 - t0;
        const float dy = x1 - t1;
        d2v = dx * dx + dy * dy;
    }

    // ---- deterministic block reduction (doubles) ----
    sd[tid] = (double)acc + (double)d2v;
    sn[tid] = (double)nv;
    __syncthreads();
    #pragma unroll
    for (int off = BLOCK1 / 2; off > 0; off >>= 1) {
        if (tid < off) {
            sd[tid] += sd[tid + off];
            sn[tid] += sn[tid + off];
        }
        __syncthreads();
    }
    if (tid == 0) {
        partials[blockIdx.x * 2 + 0] = sd[0];
        partials[blockIdx.x * 2 + 1] = sn[0];
    }
}

__global__ __launch_bounds__(256) void mse2_reduce(const double* __restrict__ partials,
                                                   float* __restrict__ out)
{
    __shared__ double ssum[256], snum[256];
    double s = 0.0, n = 0.0;
    for (int i = threadIdx.x; i < GRID1; i += 256) {
        s += partials[i * 2 + 0];
        n += partials[i * 2 + 1];
    }
    ssum[threadIdx.x] = s;
    snum[threadIdx.x] = n;
    __syncthreads();
    for (int off = 128; off; off >>= 1) {
        if (threadIdx.x < off) {
            ssum[threadIdx.x] += ssum[threadIdx.x + off];
            snum[threadIdx.x] += snum[threadIdx.x + off];
        }
        __syncthreads();
    }
    if (threadIdx.x == 0) out[0] = (float)(ssum[0] / snum[0]);
}

extern "C" void kernel_launch(void* const* d_in, const int* in_sizes, int n_in,
                              void* d_out, int out_size, void* d_ws, size_t ws_size,
                              hipStream_t stream) {
    const float* osp = (const float*)d_in[0];
    const float* h   = (const float*)d_in[1];
    // d_in[2] = op, unused by the reference
    const float* t   = (const float*)d_in[3];
    const float* v   = (const float*)d_in[4];
    double* partials = (double*)d_ws;
    float* out = (float*)d_out;

    mse2_main<<<GRID1, BLOCK1, 0, stream>>>(osp, h, t, v, partials);
    mse2_reduce<<<1, 256, 0, stream>>>(partials, out);
}